// Round 3
// baseline (1885.193 us; speedup 1.0000x reference)
//
#include <hip/hip_runtime.h>
#include <hip/hip_bf16.h>
#include <string.h>

// Problem constants
#define B_ 64
#define T_ 256
#define F_ 64
#define U_ 512
#define G4_ 2048     // 4*U
#define KTOT 576     // F + U   (input proj folded into recurrent matmul as extra K)
#define KSTEPS 18    // KTOT/32

typedef __attribute__((ext_vector_type(8))) short short8;
typedef __attribute__((ext_vector_type(4))) float v4f;
typedef unsigned short u16;

__device__ __forceinline__ float bf2f(u16 b) {
    unsigned int x = ((unsigned int)b) << 16;
    float f; memcpy(&f, &x, 4); return f;
}
__device__ __forceinline__ u16 f2bf(float f) {
    __hip_bfloat16 h = __float2bfloat16(f);
    u16 b; memcpy(&b, &h, 2); return b;
}
__device__ __forceinline__ float sigmoidf_(float x) { return 1.f / (1.f + __expf(-x)); }

// Dtype-flexible element load: fg=1 -> fp32, fg=0 -> bf16.
__device__ __forceinline__ float ldany(const void* p, size_t i, int fg) {
    return fg ? ((const float*)p)[i] : bf2f(((const u16*)p)[i]);
}

// Workspace layout (bytes; all offsets 64-aligned).  Total 5,057,664 B.
#define WS_FLAG   0
#define WS_XB     64            // bf16 [T][B][F]          2,097,152
#define WS_WP     2097216       // bf16 packed weights     2,359,296
#define WS_H2     4456512       // bf16 [2][B][U]            131,072
#define WS_C      4587584       // fp32 [B][U]               131,072
#define WS_DOT    4718656       // fp32 [B][T]                65,536
#define WS_BIASF  4784192       // fp32 [4U]                   8,192
#define WS_ATTWF  4792384       // fp32 [T][T]               262,144
#define WS_ATTBF  5054528       // fp32 [T]                    1,024
#define WS_OUTWF  5055552       // fp32 [U]                    2,048
#define WS_OUTBF  5057600       // fp32 [1]                       64
#define WS_NEED   5057664

// ---------------------------------------------------------------------------
// Kernel 0: dtype detection.  Reads 256 u32 words of `kernel` (~N(0,1)*0.05).
// bf16 data: low u16 of each word is a bf16 whose exponent field (bits 14:7)
// lies in [100,135] essentially always.  fp32 data: those bits are mantissa
// bits, uniform -> ~14% in band.  Vote threshold 200 separates by >20 sigma.
// flag: 1 = fp32 inputs, 0 = bf16 inputs.
// ---------------------------------------------------------------------------
__global__ __launch_bounds__(256) void detect(const unsigned int* __restrict__ w,
                                              int* __restrict__ flag) {
    __shared__ int votes;
    if (threadIdx.x == 0) votes = 0;
    __syncthreads();
    unsigned int v = w[threadIdx.x];
    int e = (v >> 7) & 0xFF;
    if (e >= 100 && e <= 135) atomicAdd(&votes, 1);
    __syncthreads();
    if (threadIdx.x == 0) *flag = (votes < 200) ? 1 : 0;
}

// ---------------------------------------------------------------------------
// Kernel 1: canonicalize inputs.  x -> xb bf16 [T][B][F] (transposed for
// contiguous per-step slabs); bias/attW/attb/outW/outb -> fp32; dot -> 0.
// Flat task space, grid 4428*256 >= 1,133,313.
// ---------------------------------------------------------------------------
__global__ __launch_bounds__(256) void convert(const void* __restrict__ x,
                                               const void* __restrict__ bias,
                                               const void* __restrict__ attW,
                                               const void* __restrict__ attb,
                                               const void* __restrict__ outW,
                                               const void* __restrict__ outb,
                                               const int* __restrict__ flag,
                                               u16* __restrict__ xb,
                                               float* __restrict__ biasf,
                                               float* __restrict__ attWf,
                                               float* __restrict__ attbf,
                                               float* __restrict__ outWf,
                                               float* __restrict__ outbf,
                                               float* __restrict__ dot) {
    int fg = *flag;
    size_t i = (size_t)blockIdx.x * 256 + threadIdx.x;
    if (i < 1048576) {
        float v = ldany(x, i, fg);
        int b = (int)(i >> 14), t = (int)((i >> 6) & 255), f = (int)(i & 63);
        xb[((size_t)t * B_ + b) * F_ + f] = f2bf(v);
        return;
    }
    i -= 1048576;
    if (i < 2048)  { biasf[i] = ldany(bias, i, fg); return; }
    i -= 2048;
    if (i < 65536) { attWf[i] = ldany(attW, i, fg); return; }
    i -= 65536;
    if (i < 256)   { attbf[i] = ldany(attb, i, fg); return; }
    i -= 256;
    if (i < 512)   { outWf[i] = ldany(outW, i, fg); return; }
    i -= 512;
    if (i < 1)     { outbf[i] = ldany(outb, i, fg); return; }
    i -= 1;
    if (i < 16384) { dot[i] = 0.f; return; }
}

// ---------------------------------------------------------------------------
// Kernel 2: pack [kernel(64,2048); rec_kernel(512,2048)] into MFMA-B-fragment
// layout, column permutation c' = 4*u + gate (orig col = gate*512 + u) so a
// 32-col slice holds all 4 gates of 8 hidden units.  Lane l of fragment
// (nt, ks) supplies B[k = ks*32 + (l>>4)*8 + j][col = nt*16 + (l&15)], stored
// lane-contiguous 16B.
// ---------------------------------------------------------------------------
__global__ __launch_bounds__(256) void pack_w(const void* __restrict__ kin,
                                              const void* __restrict__ krec,
                                              const int* __restrict__ flag,
                                              u16* __restrict__ Wp) {
    int fg = *flag;
    int gid = blockIdx.x * 256 + threadIdx.x;   // grid = 576*256 == 128*18*64
    int lane = gid & 63;
    int frag = gid >> 6;
    int nt = frag / KSTEPS;
    int ks = frag - nt * KSTEPS;
    int kbase = ks * 32 + (lane >> 4) * 8;
    int cp = nt * 16 + (lane & 15);
    int u = cp >> 2, gate = cp & 3;
    int C = gate * U_ + u;
    short8 v;
    for (int j = 0; j < 8; j++) {
        int k = kbase + j;
        float w = (k < F_) ? ldany(kin, (size_t)k * G4_ + C, fg)
                           : ldany(krec, (size_t)(k - F_) * G4_ + C, fg);
        v[j] = (short)f2bf(w);
    }
    *reinterpret_cast<short8*>(Wp + (size_t)gid * 8) = v;
}

// ---------------------------------------------------------------------------
// Kernel 3: one LSTM timestep.  grid = 64 blocks (block b owns hidden units
// [8b,8b+8) == packed cols [32b,32b+32)), 256 threads = 4 waves, wave w owns
// batch rows [16w,16w+16).  G = [x_t | h_{t-1}] @ Wp (K=576, fp32 acc), then
// block-local gate nonlinearity + c/h update (c fp32, h bf16 ping-pong), and
// the fused output dot <h_t[b], out_W> accumulated into dot[b][t].
// ---------------------------------------------------------------------------
__global__ __launch_bounds__(256) void lstm_step(const u16* __restrict__ xb,   // [T][B][F] bf16
                                                 const float* __restrict__ biasf,
                                                 const float* __restrict__ outWf,
                                                 const u16* __restrict__ Wp,
                                                 const u16* __restrict__ hprev,
                                                 u16* __restrict__ hcur,
                                                 float* __restrict__ c,
                                                 float* __restrict__ dot,
                                                 int t) {
    __shared__ __align__(16) u16 Bs[KSTEPS * 2 * 64 * 8];   // 36 KB
    __shared__ __align__(16) float gbuf[64][32];            // 8 KB

    int tid = threadIdx.x;
    int b = blockIdx.x;

    // Stage the block's B-slice (n-tiles 2b, 2b+1) into LDS: 2304 16B chunks.
    for (int i = 0; i < 9; i++) {
        int chunk = i * 256 + tid;            // 0..2303
        int ks = chunk >> 7;
        int rem = chunk & 127;
        int tile = rem >> 6;
        int lane = rem & 63;
        int nt = 2 * b + tile;
        short8 v = *reinterpret_cast<const short8*>(Wp + ((size_t)(nt * KSTEPS + ks) * 64 + lane) * 8);
        *reinterpret_cast<short8*>(&Bs[((ks * 2 + tile) * 64 + lane) * 8]) = v;
    }
    __syncthreads();

    int w = tid >> 6, lane = tid & 63;
    int arow = w * 16 + (lane & 15);          // A-operand row (batch index)
    int koff = (lane >> 4) * 8;
    v4f acc0 = {0.f, 0.f, 0.f, 0.f}, acc1 = {0.f, 0.f, 0.f, 0.f};
    int kmax = (t == 0) ? 2 : KSTEPS;         // t==0: h_prev == 0, only x@K part
    const u16* xrow = xb + ((size_t)t * B_ + arow) * F_;
    const u16* hrow = hprev + (size_t)arow * U_;

    for (int ks = 0; ks < kmax; ks++) {
        int k = ks * 32 + koff;
        const u16* ap = (k < F_) ? (xrow + k) : (hrow + (k - F_));
        short8 a = *reinterpret_cast<const short8*>(ap);
        short8 b0 = *reinterpret_cast<const short8*>(&Bs[((ks * 2 + 0) * 64 + lane) * 8]);
        short8 b1 = *reinterpret_cast<const short8*>(&Bs[((ks * 2 + 1) * 64 + lane) * 8]);
        acc0 = __builtin_amdgcn_mfma_f32_16x16x32_bf16(a, b0, acc0, 0, 0, 0);
        acc1 = __builtin_amdgcn_mfma_f32_16x16x32_bf16(a, b1, acc1, 0, 0, 0);
    }

    // D layout: lane holds D[row=(l>>4)*4+r][col=l&15]  (verified m89/m91)
    {
        int col0 = lane & 15;
        int rbase = w * 16 + (lane >> 4) * 4;
        for (int r = 0; r < 4; r++) {
            gbuf[rbase + r][col0]      = acc0[r];
            gbuf[rbase + r][16 + col0] = acc1[r];
        }
    }
    __syncthreads();

    // Elementwise update: 512 items (64 rows x 8 local u), 2 per thread.
    // Cols of gbuf are packed as 4*ui + gate.
    for (int it = 0; it < 2; it++) {
        int item = it * 256 + tid;
        int r  = item >> 3;
        int ui = item & 7;                    // == tid & 7
        int cl = ui * 4;
        int ug = b * 8 + ui;                  // global hidden unit
        float gi = gbuf[r][cl + 0] + biasf[0 * U_ + ug];
        float gf = gbuf[r][cl + 1] + biasf[1 * U_ + ug];
        float gg = gbuf[r][cl + 2] + biasf[2 * U_ + ug];
        float go = gbuf[r][cl + 3] + biasf[3 * U_ + ug];
        float ig = sigmoidf_(gi), fg = sigmoidf_(gf), og = sigmoidf_(go);
        float gc = tanhf(gg);
        float cold = (t == 0) ? 0.f : c[(size_t)r * U_ + ug];
        float cn = fg * cold + ig * gc;
        c[(size_t)r * U_ + ug] = cn;
        float h = og * tanhf(cn);
        hcur[(size_t)r * U_ + ug] = f2bf(h);

        // Fused output dot: 8 lanes (same r) reduce h*outW over their units.
        float hw = h * outWf[ug];
        hw += __shfl_xor(hw, 1, 64);
        hw += __shfl_xor(hw, 2, 64);
        hw += __shfl_xor(hw, 4, 64);
        if ((tid & 7) == 0) atomicAdd(&dot[(size_t)r * T_ + t], hw);
    }
}

// ---------------------------------------------------------------------------
// Kernel 4: finale.  attention collapses to scalars:
//   coef_t = (t==0) ? 1 : sum_{j<t} att_W[t,j];  shift_t = (t==0) ? 0 : att_b[t]
//   out[b,t] = sigmoid(coef_t * dot[b,t] + shift_t * sum(out_W) + out_b)
// grid = 256 (one block per t).  Output dtype follows the input dtype flag.
// ---------------------------------------------------------------------------
__global__ __launch_bounds__(256) void finale(const float* __restrict__ attWf,
                                              const float* __restrict__ attbf,
                                              const float* __restrict__ outWf,
                                              const float* __restrict__ outbf,
                                              const float* __restrict__ dot,
                                              const int* __restrict__ flag,
                                              void* __restrict__ out) {
    __shared__ float red[256];
    int t = blockIdx.x, tid = threadIdx.x;
    int fg = *flag;

    float v = (tid < t) ? attWf[(size_t)t * T_ + tid] : 0.f;
    red[tid] = v; __syncthreads();
    for (int s = 128; s > 0; s >>= 1) { if (tid < s) red[tid] += red[tid + s]; __syncthreads(); }
    float coef = (t == 0) ? 1.f : red[0];
    __syncthreads();
    red[tid] = outWf[tid] + outWf[tid + 256]; __syncthreads();
    for (int s = 128; s > 0; s >>= 1) { if (tid < s) red[tid] += red[tid + s]; __syncthreads(); }
    float sumW = red[0];

    float base = ((t == 0) ? 0.f : attbf[t]) * sumW + outbf[0];

    if (tid < B_) {
        float s = sigmoidf_(coef * dot[(size_t)tid * T_ + t] + base);
        size_t idx = (size_t)tid * T_ + t;
        if (fg) ((float*)out)[idx] = s;
        else    ((u16*)out)[idx] = f2bf(s);
    }
}

// ---------------------------------------------------------------------------
extern "C" void kernel_launch(void* const* d_in, const int* in_sizes, int n_in,
                              void* d_out, int out_size, void* d_ws, size_t ws_size,
                              hipStream_t stream) {
    const void* x    = d_in[0];   // inputs (64,256,64)
    const void* kin  = d_in[1];   // kernel (64,2048)
    const void* krec = d_in[2];   // rec_kernel (512,2048)
    const void* bias = d_in[3];   // (2048,)
    const void* attW = d_in[4];   // (256,256)
    const void* attb = d_in[5];   // (256,)
    const void* outW = d_in[6];   // (512,)
    const void* outb = d_in[7];   // ()

    if (ws_size < (size_t)WS_NEED) return;   // diagnostic: output stays memset-0

    char* ws = (char*)d_ws;
    int*   flag  = (int*)(ws + WS_FLAG);
    u16*   xb    = (u16*)(ws + WS_XB);
    u16*   Wp    = (u16*)(ws + WS_WP);
    u16*   h2    = (u16*)(ws + WS_H2);       // [2][64][512] bf16 ping-pong
    float* c     = (float*)(ws + WS_C);
    float* dot   = (float*)(ws + WS_DOT);
    float* biasf = (float*)(ws + WS_BIASF);
    float* attWf = (float*)(ws + WS_ATTWF);
    float* attbf = (float*)(ws + WS_ATTBF);
    float* outWf = (float*)(ws + WS_OUTWF);
    float* outbf = (float*)(ws + WS_OUTBF);

    detect<<<1, 256, 0, stream>>>((const unsigned int*)kin, flag);
    convert<<<4428, 256, 0, stream>>>(x, bias, attW, attb, outW, outb, flag,
                                      xb, biasf, attWf, attbf, outWf, outbf, dot);
    pack_w<<<576, 256, 0, stream>>>(kin, krec, flag, Wp);
    for (int t = 0; t < T_; t++) {
        u16* hcur  = h2 + (size_t)(t & 1) * (B_ * U_);
        u16* hprev = h2 + (size_t)((t + 1) & 1) * (B_ * U_);
        lstm_step<<<64, 256, 0, stream>>>(xb, biasf, outWf, Wp, hprev, hcur, c, dot, t);
    }
    finale<<<256, 256, 0, stream>>>(attWf, attbf, outWf, outbf, dot, flag, d_out);
}